// Round 8
// baseline (313.767 us; speedup 1.0000x reference)
//
#include <hip/hip_runtime.h>

// Problem: L=200 events in pairs -> S=100 scan steps over u[N,N,3], N=256.
// Each (n,m) cell is an independent 100-step chain.
//
// History: r1 scattered ring / r4 4-lane / r7 LDS-staged+counted-vmcnt all
// land ~0.9-1.0 us per serial step (kernel ~105 us) with VALU 7%, BW 18%,
// conflicts 0 -> no pipe busy; the serial chain latency IS the bottleneck,
// memory org is irrelevant. FETCH identical (128.5 MB) scattered vs staged.
//
// This round: SEGMENTED scan. softmax Jacobian norm <= 1/4 -> the step map
// contracts initial-state error >=4x/step. Segment k in [1,3] starts 15
// steps early from u_begin (wrong state); after 15 warmup steps the state
// error is (1/4)^15 ~ 1e-9, far below the existing 2^-8 absmax. Serial
// steps/thread: 100 -> 40; blocks 256 -> 1024 (16 waves/CU, 4/SIMD) so the
// per-step stall is hidden by wave interleave. a-traffic x1.45 (acceptable:
// memory was never the limit). f stays in a separate high-occupancy kernel
// (verified r4/r5) so w/ev is read once.
//
// Layout: event_list[201,256,256], a[200,256,256,3], w[200,256,1,256],
//         u_begin[256,256,3], liner_w[256,3], liner_b[256], out[100,256,256].

#define NN    256
#define TT    200
#define SS    100
#define NSEG  4
#define SEGO  25           // outputs per segment
#define WARM  15           // warmup steps for segments 1..3

// ---------------- kernel 1: f[t,n] = exp(-dot*time), high occupancy ----------
__global__ __launch_bounds__(256) void f_kernel(
    const float* __restrict__ timep,   // [2]
    const float* __restrict__ ev,      // [201,N,N]
    const float* __restrict__ w,       // [T,N,1,N]
    float* __restrict__ fws)           // [N,T] workspace
{
    const int tid  = threadIdx.x;
    const int lane = tid & 63;
    const int row  = blockIdx.x * 4 + (tid >> 6);   // 0..51199
    const int t    = row >> 8;                      // 0..199
    const int n    = row & 255;

    const size_t off = (size_t)t * (NN * NN) + (size_t)n * NN;
    const float4 wv  = ((const float4*)(w  + off))[lane];
    const float4 evv = ((const float4*)(ev + off))[lane];

    float d = wv.x * evv.x;
    d = fmaf(wv.y, evv.y, d);
    d = fmaf(wv.z, evv.z, d);
    d = fmaf(wv.w, evv.w, d);
#pragma unroll
    for (int o = 1; o < 64; o <<= 1) d += __shfl_xor(d, o, 64);

    if (lane == 0) {
        const float tsel = (t & 1) ? timep[1] : timep[0];
        fws[n * TT + t] = __expf(-d * tsel);
    }
}

// ---------------- kernel 2: segmented scan, 1 thread per chain ----------------
__global__ __launch_bounds__(256, 4) void seg_scan_kernel(
    const float* __restrict__ fws,     // [N,T]
    const float* __restrict__ ub,      // [N,N,3]
    const float* __restrict__ a,       // [T,N,N,3]
    const float* __restrict__ lw,      // [N,3]
    const float* __restrict__ lb,      // [N]
    float* __restrict__ out)           // [S,N,N]
{
    __shared__ float fsl[TT];

    const int n   = blockIdx.x;
    const int seg = blockIdx.y;              // 0..3
    const int tid = threadIdx.x;             // chain m

    const int s0 = seg * SEGO;               // first output step
    const int sb = (seg == 0) ? 0 : (s0 - WARM);   // first processed step
    const int se = s0 + SEGO;                // one past last step

    // stage the needed f range into LDS (<= 80 floats)
    for (int t = 2 * sb + tid; t < 2 * se; t += 256)
        fsl[t] = fws[n * TT + t];

    const size_t TS    = (size_t)NN * NN * 3;        // floats per t-slab
    const size_t cbase = (size_t)n * (NN * 3) + (size_t)tid * 3;

    // state starts from u_begin for ALL segments; warmup contracts the error
    float u0 = ub[cbase + 0];
    float u1 = ub[cbase + 1];
    float u2 = ub[cbase + 2];
    const float w0 = lw[n * 3 + 0];
    const float w1 = lw[n * 3 + 1];
    const float w2 = lw[n * 3 + 2];
    const float bb = lb[n];

    __syncthreads();

    // depth-2 rotation prefetch over steps (2 slabs, 6 floats per step)
    const float* ap = a + (size_t)(2 * sb) * TS + cbase;
    float c0x = ap[0],           c0y = ap[1],           c0z = ap[2];
    float c1x = ap[TS + 0],      c1y = ap[TS + 1],      c1z = ap[TS + 2];
    const float* ap1 = ap + 2 * TS;
    float n0x = ap1[0],          n0y = ap1[1],          n0z = ap1[2];
    float n1x = ap1[TS + 0],     n1y = ap1[TS + 1],     n1z = ap1[TS + 2];

    float* op = out + (size_t)n * NN + tid;

    for (int s = sb; s < se; ++s) {
        // prefetch step s+2 (clamped to sb at the tail: harmless re-read)
        const int sp = (s + 2 < se) ? (s + 2) : sb;
        const float* app = a + (size_t)(2 * sp) * TS + cbase;
        float p0x = app[0];
        float p0y = app[1];
        float p0z = app[2];
        float p1x = app[TS + 0];
        float p1y = app[TS + 1];
        float p1z = app[TS + 2];

        const float f0 = fsl[2 * s];
        const float f1 = fsl[2 * s + 1];

        float l0 = fmaf(c0x, f0, fmaf(c1x, f1, u0));
        float l1 = fmaf(c0y, f0, fmaf(c1y, f1, u1));
        float l2 = fmaf(c0z, f0, fmaf(c1z, f1, u2));
        float mx = fmaxf(l0, fmaxf(l1, l2));
        float e0 = __expf(l0 - mx);
        float e1 = __expf(l1 - mx);
        float e2 = __expf(l2 - mx);
        float iv = __builtin_amdgcn_rcpf(e0 + e1 + e2);
        u0 = e0 * iv;
        u1 = e1 * iv;
        u2 = e2 * iv;

        if (s >= s0) {   // block-uniform guard: warmup steps don't store
            __builtin_nontemporal_store(
                fmaf(u0, w0, fmaf(u1, w1, fmaf(u2, w2, bb))),
                op + (size_t)s * (NN * NN));
        }

        // rotate prefetch registers
        c0x = n0x; c0y = n0y; c0z = n0z;
        c1x = n1x; c1y = n1y; c1z = n1z;
        n0x = p0x; n0y = p0y; n0z = p0z;
        n1x = p1x; n1y = p1y; n1z = p1z;
    }
}

extern "C" void kernel_launch(void* const* d_in, const int* in_sizes, int n_in,
                              void* d_out, int out_size, void* d_ws, size_t ws_size,
                              hipStream_t stream) {
    const float* timep = (const float*)d_in[0];
    const float* ev    = (const float*)d_in[1];
    const float* ub    = (const float*)d_in[2];
    const float* a     = (const float*)d_in[3];
    const float* w     = (const float*)d_in[4];
    const float* lw    = (const float*)d_in[5];
    const float* lb    = (const float*)d_in[6];
    float* out = (float*)d_out;
    float* fws = (float*)d_ws;                 // needs 256*200*4 = 204800 B

    f_kernel<<<(TT * NN) / 4, 256, 0, stream>>>(timep, ev, w, fws);
    seg_scan_kernel<<<dim3(NN, NSEG), 256, 0, stream>>>(fws, ub, a, lw, lb, out);
}